// Round 7
// baseline (101.245 us; speedup 1.0000x reference)
//
#include <hip/hip_runtime.h>
#include <hip/hip_bf16.h>

// LocalKNN: B=64, Way=5, D=64, Nq=1024, Ns=1024, K=3.
// out[b,w] = sum_q rnq[q] * sum(top3_s( <q_bq, shat_bws> ))
// Round 7: S streamed via LDS ring (8 x 4KB) staged with global_load_lds(16B),
// counted s_waitcnt vmcnt(4) + raw s_barrier (never drain-to-0 in loop).
// Register ring prefetch (r4-r6) couldn't beat L3 latency; DMA-to-LDS decouples
// lookahead from register pressure (T3/T4 pattern).

using bf16x8 = __attribute__((ext_vector_type(8))) short;  // 8 bf16 = 4 VGPRs
using f32x4  = __attribute__((ext_vector_type(4))) float;

__device__ inline unsigned cvt_pk_bf16(float lo, float hi) {
    unsigned r;
    asm("v_cvt_pk_bf16_f32 %0, %1, %2" : "=v"(r) : "v"(lo), "v"(hi));
    return r;
}

__device__ inline uint4 pack8cvt(const float* v) {
    uint4 r;
    r.x = cvt_pk_bf16(v[0], v[1]);
    r.y = cvt_pk_bf16(v[2], v[3]);
    r.z = cvt_pk_bf16(v[4], v[5]);
    r.w = cvt_pk_bf16(v[6], v[7]);
    return r;
}

// branchless insert of v into sorted top-3 (t0>=t1>=t2): 1 max + 2 med3
#define INS(v, T0, T1, T2) do {                         \
    float _v = (v);                                     \
    float _n0 = fmaxf((T0), _v);                        \
    float _n1 = __builtin_amdgcn_fmed3f(_v, (T0), (T1));\
    float _n2 = __builtin_amdgcn_fmed3f(_v, (T1), (T2));\
    (T0) = _n0; (T1) = _n1; (T2) = _n2;                 \
} while (0)

// async 16B/lane global->LDS (LDS dest = wave-uniform base + lane*16)
__device__ inline void gload16(const void* g, void* lds) {
    __builtin_amdgcn_global_load_lds(
        (const __attribute__((address_space(1))) unsigned int*)g,
        (__attribute__((address_space(3))) unsigned int*)lds,
        16, 0, 0);
}

// ============================= fast path =====================================
// Fragment layout: per 16-col tile, 128 uint4 slots; slot h*16 + r holds
// column (tile*16+r)'s elements d = 8h..8h+7 as 4 packed bf16-pairs.
// MFMA read: slot c*64 + lane -> lane holds col r=lane&15, k = c*32 + (lane>>4)*8 + j.

// ---- prep_all: raw Q/S -> bf16 fragments (+ rnq) ----------------------------
__global__ __launch_bounds__(256) void prep_all(const float* __restrict__ Q,
                                                const float* __restrict__ S,
                                                uint4* __restrict__ Qbf,
                                                uint4* __restrict__ Sbf,
                                                float* __restrict__ rnq) {
    const int blk = blockIdx.x;
    if (blk < 256) {
        const int b = blk >> 2;
        const int col = ((blk & 3) << 8) + threadIdx.x;      // q in 0..1023
        const float* p = Q + (size_t)b * 65536 + col;
        float v[64];
        #pragma unroll
        for (int d = 0; d < 64; ++d) v[d] = p[(size_t)d << 10];
        float ss = 0.f;
        #pragma unroll
        for (int d = 0; d < 64; ++d) ss += v[d] * v[d];
        rnq[(b << 10) + col] = 1.0f / fmaxf(sqrtf(ss), 1e-12f);
        uint4* ob = Qbf + ((size_t)(b << 6) + (col >> 4)) * 128 + (col & 15);
        #pragma unroll
        for (int h = 0; h < 8; ++h)
            ob[h << 4] = pack8cvt(&v[h << 3]);
    } else {
        const int bw = (blk - 256) >> 2;
        const int col = ((blk & 3) << 8) + threadIdx.x;      // s in 0..1023
        const float* p = S + (size_t)bw * 65536 + col;
        float v[64];
        #pragma unroll
        for (int d = 0; d < 64; ++d) v[d] = p[(size_t)d << 10];
        float ss = 0.f;
        #pragma unroll
        for (int d = 0; d < 64; ++d) ss += v[d] * v[d];
        const float rs = 1.0f / fmaxf(sqrtf(ss), 1e-12f);
        #pragma unroll
        for (int d = 0; d < 64; ++d) v[d] *= rs;
        uint4* ob = Sbf + ((size_t)(bw << 6) + (col >> 4)) * 128 + (col & 15);
        #pragma unroll
        for (int h = 0; h < 8; ++h)
            ob[h << 4] = pack8cvt(&v[h << 3]);
    }
}

// ---- main: LDS-pipelined fused GEMM + top-3 ---------------------------------
// 1-D grid 1280 (logical l: qc = l&3, bw = l>>2), block = 256 (4 waves).
// Wave wv holds q-tiles qc*16+wv*4+{0..3} in regs; S streams through an 8-slot
// LDS ring of tile-PAIRS (4KB each), staged 4 pairs ahead by global_load_lds.
__global__ __launch_bounds__(256) void knn_main(const uint4* __restrict__ Qbf,
                                                const uint4* __restrict__ Sbf,
                                                const float* __restrict__ rnq,
                                                float* __restrict__ partial) {
    __shared__ uint4 ring[8 * 256];     // 8 pair-slots x 4 KB = 32 KB
    __shared__ float wsum[4];
    const int lin = blockIdx.x;
    const int l   = (lin & 7) * 160 + (lin >> 3);   // 1280 = 8*160, bijective
    const int qc  = l & 3;
    const int bw  = l >> 2;                          // b*5 + w
    const int b   = bw / 5;
    const int wv = threadIdx.x >> 6, lane = threadIdx.x & 63;

    // Q fragments: one-time global read
    const uint4* qb = Qbf + ((size_t)(b << 6) + (qc << 4) + (wv << 2)) * 128 + lane;
    bf16x8 bq[4][2];
    #pragma unroll
    for (int qt = 0; qt < 4; ++qt)
        #pragma unroll
        for (int c = 0; c < 2; ++c)
            bq[qt][c] = *reinterpret_cast<const bf16x8*>(&qb[qt * 128 + (c << 6)]);

    const char* sbase = (const char*)(Sbf + (size_t)(bw << 6) * 128);
    const size_t toff = (size_t)threadIdx.x * 16;    // block stages 4KB/pair

    float t0[4], t1[4], t2[4];
    #pragma unroll
    for (int qt = 0; qt < 4; ++qt) { t0[qt] = -1e30f; t1[qt] = -1e30f; t2[qt] = -1e30f; }

    // prologue: stage pairs 0..3
    #pragma unroll
    for (int p = 0; p < 4; ++p)
        gload16(sbase + (size_t)p * 4096 + toff, &ring[(p << 8) + (wv << 6)]);

    // main loop: 32 pairs of s-tiles; stage 4 ahead, counted vmcnt, raw barrier
    for (int p = 0; p < 28; ++p) {
        gload16(sbase + (size_t)(p + 4) * 4096 + toff,
                &ring[(((p + 4) & 7) << 8) + (wv << 6)]);
        asm volatile("s_waitcnt vmcnt(4)" ::: "memory");
        __builtin_amdgcn_s_barrier();
        const uint4* sp = &ring[((p & 7) << 8)];
        #pragma unroll
        for (int tt = 0; tt < 2; ++tt) {
            bf16x8 a0 = *reinterpret_cast<const bf16x8*>(&sp[tt * 128 + lane]);
            bf16x8 a1 = *reinterpret_cast<const bf16x8*>(&sp[tt * 128 + 64 + lane]);
            #pragma unroll
            for (int qt = 0; qt < 4; ++qt) {
                f32x4 c = {0.f, 0.f, 0.f, 0.f};
                c = __builtin_amdgcn_mfma_f32_16x16x32_bf16(a0, bq[qt][0], c, 0, 0, 0);
                c = __builtin_amdgcn_mfma_f32_16x16x32_bf16(a1, bq[qt][1], c, 0, 0, 0);
                #pragma unroll
                for (int j = 0; j < 4; ++j)
                    INS(c[j], t0[qt], t1[qt], t2[qt]);
            }
        }
        __builtin_amdgcn_s_barrier();
    }
    // tail: everything staged; drain once, no more barriers needed
    asm volatile("s_waitcnt vmcnt(0)" ::: "memory");
    __builtin_amdgcn_s_barrier();
    for (int p = 28; p < 32; ++p) {
        const uint4* sp = &ring[((p & 7) << 8)];
        #pragma unroll
        for (int tt = 0; tt < 2; ++tt) {
            bf16x8 a0 = *reinterpret_cast<const bf16x8*>(&sp[tt * 128 + lane]);
            bf16x8 a1 = *reinterpret_cast<const bf16x8*>(&sp[tt * 128 + 64 + lane]);
            #pragma unroll
            for (int qt = 0; qt < 4; ++qt) {
                f32x4 c = {0.f, 0.f, 0.f, 0.f};
                c = __builtin_amdgcn_mfma_f32_16x16x32_bf16(a0, bq[qt][0], c, 0, 0, 0);
                c = __builtin_amdgcn_mfma_f32_16x16x32_bf16(a1, bq[qt][1], c, 0, 0, 0);
                #pragma unroll
                for (int j = 0; j < 4; ++j)
                    INS(c[j], t0[qt], t1[qt], t2[qt]);
            }
        }
    }

    // merge top-3 across the 4 lane-groups sharing each q; apply rnq
    float s3 = 0.f;
    #pragma unroll
    for (int qt = 0; qt < 4; ++qt) {
        #pragma unroll
        for (int m = 16; m <= 32; m <<= 1) {
            float b0 = __shfl_xor(t0[qt], m);
            float b1 = __shfl_xor(t1[qt], m);
            float b2 = __shfl_xor(t2[qt], m);
            INS(b0, t0[qt], t1[qt], t2[qt]);
            INS(b1, t0[qt], t1[qt], t2[qt]);
            INS(b2, t0[qt], t1[qt], t2[qt]);
        }
        const int qg = (qc << 8) + (wv << 6) + (qt << 4) + (lane & 15);
        s3 += (t0[qt] + t1[qt] + t2[qt]) * rnq[(b << 10) + qg];
    }
    #pragma unroll
    for (int m = 1; m < 64; m <<= 1) s3 += __shfl_xor(s3, m);
    s3 *= 0.25f;                       // each q replicated over 4 lane-groups
    if (lane == 0) wsum[wv] = s3;
    __syncthreads();
    if (threadIdx.x == 0)
        partial[((size_t)bw << 2) + qc] = (wsum[0] + wsum[1]) + (wsum[2] + wsum[3]);
}

__global__ void finalize4(const float* __restrict__ partial, float* __restrict__ out) {
    int i = blockIdx.x * blockDim.x + threadIdx.x;
    if (i < 320)
        out[i] = (partial[4 * i] + partial[4 * i + 1]) +
                 (partial[4 * i + 2] + partial[4 * i + 3]);
}

// ============================ fallback path (round-2) ========================
__global__ void norms_kernel(const float* __restrict__ Q, const float* __restrict__ S,
                             float* __restrict__ rnq, float* __restrict__ rns) {
    int gid = blockIdx.x * blockDim.x + threadIdx.x;
    if (gid < 65536) {
        int b = gid >> 10, qi = gid & 1023;
        const float* p = Q + (size_t)b * 65536 + qi;
        float ss = 0.f;
        #pragma unroll
        for (int d = 0; d < 64; ++d) { float v = p[(size_t)d * 1024]; ss += v * v; }
        rnq[gid] = 1.0f / fmaxf(sqrtf(ss), 1e-12f);
    } else {
        int v = gid - 65536;
        int bw = v >> 10, si = v & 1023;
        const float* p = S + (size_t)bw * 65536 + si;
        float ss = 0.f;
        #pragma unroll
        for (int d = 0; d < 64; ++d) { float x = p[(size_t)d * 1024]; ss += x * x; }
        rns[v] = 1.0f / fmaxf(sqrtf(ss), 1e-12f);
    }
}

__global__ __launch_bounds__(512, 4) void knn_fb(
        const float* __restrict__ Q, const float* __restrict__ S,
        const float* __restrict__ rnq, const float* __restrict__ rns,
        float* __restrict__ partial) {
    __shared__ uint4 qfrag[16 * 128];
    __shared__ uint4 sfrag[2][4 * 128];
    __shared__ float wsum[8];

    const int qc = blockIdx.x, w = blockIdx.y, b = blockIdx.z;
    const int t = threadIdx.x, wv = t >> 6, lane = t & 63;

    const float* Qb   = Q + (size_t)b * 65536;
    const float* Sb   = S + (size_t)(b * 5 + w) * 65536;
    const float* rnqb = rnq + (b << 10);
    const float* rnsb = rns + ((b * 5 + w) << 10);

    bf16x8 bq[4][2];
    for (int ph = 0; ph < 2; ++ph) {
        for (int sub = 0; sub < 4; ++sub) {
            int qg = (qc << 9) + (ph << 8) + (sub << 6) + lane;
            float v[8];
            #pragma unroll
            for (int i = 0; i < 8; ++i)
                v[i] = Qb[(size_t)((wv << 3) + i) * 1024 + qg];
            qfrag[((sub << 2) + (lane >> 4)) * 128 + (wv << 4) + (lane & 15)] = pack8cvt(v);
        }
        __syncthreads();
        if ((wv >> 2) == ph) {
            #pragma unroll
            for (int qt = 0; qt < 4; ++qt)
                #pragma unroll
                for (int c = 0; c < 2; ++c)
                    bq[qt][c] = *reinterpret_cast<const bf16x8*>(
                        &qfrag[(((wv & 3) << 2) + qt) * 128 + (c << 6) + lane]);
        }
        __syncthreads();
    }

    {
        float sv[8]; float rs = rnsb[lane];
        #pragma unroll
        for (int i = 0; i < 8; ++i)
            sv[i] = Sb[(size_t)((wv << 3) + i) * 1024 + lane] * rs;
        sfrag[0][(lane >> 4) * 128 + (wv << 4) + (lane & 15)] = pack8cvt(sv);
    }
    __syncthreads();

    float t0[4], t1[4], t2[4];
    #pragma unroll
    for (int qt = 0; qt < 4; ++qt) { t0[qt] = -1e30f; t1[qt] = -1e30f; t2[qt] = -1e30f; }
    int cur = 0;
    const float* sp = Sb + ((wv << 3) << 10) + lane;

    for (int blk = 0; blk < 16; ++blk) {
        float sv[8]; float rs;
        if (blk < 15) {
            const int sb_ = (blk + 1) << 6;
            rs = rnsb[sb_ + lane];
            #pragma unroll
            for (int i = 0; i < 8; ++i)
                sv[i] = sp[(size_t)(i << 10) + sb_];
        }
        #pragma unroll
        for (int st = 0; st < 4; ++st) {
            bf16x8 a0 = *reinterpret_cast<const bf16x8*>(&sfrag[cur][st * 128 + lane]);
            bf16x8 a1 = *reinterpret_cast<const bf16x8*>(&sfrag[cur][st * 128 + 64 + lane]);
            #pragma unroll
            for (int qt = 0; qt < 4; ++qt) {
                f32x4 c = {0.f, 0.f, 0.f, 0.f};
                c = __builtin_amdgcn_mfma_f32_16x16x32_bf16(a0, bq[qt][0], c, 0, 0, 0);
                c = __builtin_amdgcn_mfma_f32_16x16x32_bf16(a1, bq[qt][1], c, 0, 0, 0);
                #pragma unroll
                for (int j = 0; j < 4; ++j)
                    INS(c[j], t0[qt], t1[qt], t2[qt]);
            }
        }
        if (blk < 15) {
            #pragma unroll
            for (int i = 0; i < 8; ++i) sv[i] *= rs;
            sfrag[cur ^ 1][(lane >> 4) * 128 + (wv << 4) + (lane & 15)] = pack8cvt(sv);
        }
        __syncthreads();
        cur ^= 1;
    }

    float s3 = 0.f;
    #pragma unroll
    for (int qt = 0; qt < 4; ++qt) {
        #pragma unroll
        for (int m = 16; m <= 32; m <<= 1) {
            float b0 = __shfl_xor(t0[qt], m);
            float b1 = __shfl_xor(t1[qt], m);
            float b2 = __shfl_xor(t2[qt], m);
            INS(b0, t0[qt], t1[qt], t2[qt]);
            INS(b1, t0[qt], t1[qt], t2[qt]);
            INS(b2, t0[qt], t1[qt], t2[qt]);
        }
        int qg = (qc << 9) + (wv << 6) + (qt << 4) + (lane & 15);
        s3 += (t0[qt] + t1[qt] + t2[qt]) * rnqb[qg];
    }
    #pragma unroll
    for (int m = 1; m < 64; m <<= 1) s3 += __shfl_xor(s3, m);
    s3 *= 0.25f;
    if (lane == 0) wsum[wv] = s3;
    __syncthreads();
    if (t == 0) {
        float acc = 0.f;
        #pragma unroll
        for (int i = 0; i < 8; ++i) acc += wsum[i];
        partial[((b * 5 + w) << 1) + qc] = acc;
    }
}

__global__ void finalize2(const float* __restrict__ partial, float* __restrict__ out) {
    int i = blockIdx.x * blockDim.x + threadIdx.x;
    if (i < 320)
        out[i] = partial[2 * i] + partial[2 * i + 1];
}

// =============================================================================
extern "C" void kernel_launch(void* const* d_in, const int* in_sizes, int n_in,
                              void* d_out, int out_size, void* d_ws, size_t ws_size,
                              hipStream_t stream) {
    const float* Q = (const float*)d_in[0];   // (64,64,32,32)
    const float* S = (const float*)d_in[1];   // (64,5,64,1024)
    float* out = (float*)d_out;               // (64,5)

    // fast-path ws: Qbf 8 MB | Sbf 41.9 MB | rnq 256 KB | partial 5 KB
    const size_t QBF = 8388608ull, SBF = 41943040ull, RNQ = 262144ull;
    const size_t NEED = QBF + SBF + RNQ + 5120ull;
    if (ws_size >= NEED) {
        char* base = (char*)d_ws;
        uint4* Qbf     = (uint4*)base;
        uint4* Sbf     = (uint4*)(base + QBF);
        float* rnq     = (float*)(base + QBF + SBF);
        float* partial = (float*)(base + QBF + SBF + RNQ);
        prep_all<<<1536, 256, 0, stream>>>(Q, S, Qbf, Sbf, rnq);
        knn_main<<<1280, 256, 0, stream>>>(Qbf, Sbf, rnq, partial);
        finalize4<<<2, 256, 0, stream>>>(partial, out);
    } else {
        float* rnq = (float*)d_ws;
        float* rns = rnq + 65536;
        float* partial = rns + 327680;
        norms_kernel<<<(65536 + 327680) / 256, 256, 0, stream>>>(Q, S, rnq, rns);
        knn_fb<<<dim3(2, 5, 64), 512, 0, stream>>>(Q, S, rnq, rns, partial);
        finalize2<<<2, 256, 0, stream>>>(partial, out);
    }
}

// Round 8
// 93.816 us; speedup vs baseline: 1.0792x; 1.0792x over previous
//
#include <hip/hip_runtime.h>
#include <hip/hip_bf16.h>

// LocalKNN: B=64, Way=5, D=64, Nq=1024, Ns=1024, K=3.
// out[b,w] = sum_q rnq[q] * sum(top3_s( <q_bq, shat_bws> ))
// Round 8: same LDS-ring skeleton as r7, but the compute is re-scheduled:
//  - __launch_bounds__(256,4): 128-VGPR budget (r7's implicit cap of ~52 regs
//    forced serialized mfma->INS with exposed hazards)
//  - batch 16 MFMAs into 8 named accumulators, THEN 96 INS ops (dep-clean)
//  - opaque zero C-operand kills 32 v_mov accumulator re-inits per iter

using bf16x8 = __attribute__((ext_vector_type(8))) short;  // 8 bf16 = 4 VGPRs
using f32x4  = __attribute__((ext_vector_type(4))) float;

__device__ inline unsigned cvt_pk_bf16(float lo, float hi) {
    unsigned r;
    asm("v_cvt_pk_bf16_f32 %0, %1, %2" : "=v"(r) : "v"(lo), "v"(hi));
    return r;
}

__device__ inline uint4 pack8cvt(const float* v) {
    uint4 r;
    r.x = cvt_pk_bf16(v[0], v[1]);
    r.y = cvt_pk_bf16(v[2], v[3]);
    r.z = cvt_pk_bf16(v[4], v[5]);
    r.w = cvt_pk_bf16(v[6], v[7]);
    return r;
}

// branchless insert of v into sorted top-3 (t0>=t1>=t2): 1 max + 2 med3
#define INS(v, T0, T1, T2) do {                         \
    float _v = (v);                                     \
    float _n0 = fmaxf((T0), _v);                        \
    float _n1 = __builtin_amdgcn_fmed3f(_v, (T0), (T1));\
    float _n2 = __builtin_amdgcn_fmed3f(_v, (T1), (T2));\
    (T0) = _n0; (T1) = _n1; (T2) = _n2;                 \
} while (0)

// async 16B/lane global->LDS (LDS dest = wave-uniform base + lane*16)
__device__ inline void gload16(const void* g, void* lds) {
    __builtin_amdgcn_global_load_lds(
        (const __attribute__((address_space(1))) unsigned int*)g,
        (__attribute__((address_space(3))) unsigned int*)lds,
        16, 0, 0);
}

// ============================= fast path =====================================
// Fragment layout: per 16-col tile, 128 uint4 slots; slot h*16 + r holds
// column (tile*16+r)'s elements d = 8h..8h+7 as 4 packed bf16-pairs.
// MFMA read: slot c*64 + lane -> lane holds col r=lane&15, k = c*32 + (lane>>4)*8 + j.

// ---- prep_all: raw Q/S -> bf16 fragments (+ rnq) ----------------------------
__global__ __launch_bounds__(256) void prep_all(const float* __restrict__ Q,
                                                const float* __restrict__ S,
                                                uint4* __restrict__ Qbf,
                                                uint4* __restrict__ Sbf,
                                                float* __restrict__ rnq) {
    const int blk = blockIdx.x;
    if (blk < 256) {
        const int b = blk >> 2;
        const int col = ((blk & 3) << 8) + threadIdx.x;      // q in 0..1023
        const float* p = Q + (size_t)b * 65536 + col;
        float v[64];
        #pragma unroll
        for (int d = 0; d < 64; ++d) v[d] = p[(size_t)d << 10];
        float ss = 0.f;
        #pragma unroll
        for (int d = 0; d < 64; ++d) ss += v[d] * v[d];
        rnq[(b << 10) + col] = 1.0f / fmaxf(sqrtf(ss), 1e-12f);
        uint4* ob = Qbf + ((size_t)(b << 6) + (col >> 4)) * 128 + (col & 15);
        #pragma unroll
        for (int h = 0; h < 8; ++h)
            ob[h << 4] = pack8cvt(&v[h << 3]);
    } else {
        const int bw = (blk - 256) >> 2;
        const int col = ((blk & 3) << 8) + threadIdx.x;      // s in 0..1023
        const float* p = S + (size_t)bw * 65536 + col;
        float v[64];
        #pragma unroll
        for (int d = 0; d < 64; ++d) v[d] = p[(size_t)d << 10];
        float ss = 0.f;
        #pragma unroll
        for (int d = 0; d < 64; ++d) ss += v[d] * v[d];
        const float rs = 1.0f / fmaxf(sqrtf(ss), 1e-12f);
        #pragma unroll
        for (int d = 0; d < 64; ++d) v[d] *= rs;
        uint4* ob = Sbf + ((size_t)(bw << 6) + (col >> 4)) * 128 + (col & 15);
        #pragma unroll
        for (int h = 0; h < 8; ++h)
            ob[h << 4] = pack8cvt(&v[h << 3]);
    }
}

// two chained MFMAs (K=64) into a fresh accumulator seeded from opaque zero
#define MFMA2(CV, A0, A1, QT)                                                   \
    f32x4 CV = __builtin_amdgcn_mfma_f32_16x16x32_bf16(A0, bq[QT][0], fz, 0, 0, 0); \
    CV = __builtin_amdgcn_mfma_f32_16x16x32_bf16(A1, bq[QT][1], CV, 0, 0, 0);

#define INS4(CV, QT)                         \
    INS(CV[0], t0[QT], t1[QT], t2[QT]);      \
    INS(CV[1], t0[QT], t1[QT], t2[QT]);      \
    INS(CV[2], t0[QT], t1[QT], t2[QT]);      \
    INS(CV[3], t0[QT], t1[QT], t2[QT]);

// one ring slot = 2 s-tiles (4 KB): batch-MFMA then batch-INS
#define COMPUTE_PAIR(SLOT)                                                   \
    do {                                                                     \
        const uint4* sp_ = &ring[(SLOT) << 8];                               \
        bf16x8 a00 = *reinterpret_cast<const bf16x8*>(&sp_[lane]);           \
        bf16x8 a01 = *reinterpret_cast<const bf16x8*>(&sp_[64 + lane]);      \
        bf16x8 a10 = *reinterpret_cast<const bf16x8*>(&sp_[128 + lane]);     \
        bf16x8 a11 = *reinterpret_cast<const bf16x8*>(&sp_[192 + lane]);     \
        MFMA2(c00, a00, a01, 0) MFMA2(c01, a00, a01, 1)                      \
        MFMA2(c02, a00, a01, 2) MFMA2(c03, a00, a01, 3)                      \
        MFMA2(c10, a10, a11, 0) MFMA2(c11, a10, a11, 1)                      \
        MFMA2(c12, a10, a11, 2) MFMA2(c13, a10, a11, 3)                      \
        INS4(c00, 0) INS4(c01, 1) INS4(c02, 2) INS4(c03, 3)                  \
        INS4(c10, 0) INS4(c11, 1) INS4(c12, 2) INS4(c13, 3)                  \
    } while (0)

// ---- main: LDS-pipelined fused GEMM + top-3 ---------------------------------
// 1-D grid 1280 (logical l: qc = l&3, bw = l>>2), block = 256 (4 waves).
// Wave wv holds q-tiles qc*16+wv*4+{0..3} in regs; S streams through an 8-slot
// LDS ring of tile-PAIRS (4KB each), staged 4 pairs ahead by global_load_lds.
__global__ __launch_bounds__(256, 4) void knn_main(const uint4* __restrict__ Qbf,
                                                   const uint4* __restrict__ Sbf,
                                                   const float* __restrict__ rnq,
                                                   float* __restrict__ partial) {
    __shared__ uint4 ring[8 * 256];     // 8 pair-slots x 4 KB = 32 KB
    __shared__ float wsum[4];
    const int lin = blockIdx.x;
    const int l   = (lin & 7) * 160 + (lin >> 3);   // 1280 = 8*160, bijective
    const int qc  = l & 3;
    const int bw  = l >> 2;                          // b*5 + w
    const int b   = bw / 5;
    const int wv = threadIdx.x >> 6, lane = threadIdx.x & 63;

    // Q fragments: one-time global read
    const uint4* qb = Qbf + ((size_t)(b << 6) + (qc << 4) + (wv << 2)) * 128 + lane;
    bf16x8 bq[4][2];
    #pragma unroll
    for (int qt = 0; qt < 4; ++qt)
        #pragma unroll
        for (int c = 0; c < 2; ++c)
            bq[qt][c] = *reinterpret_cast<const bf16x8*>(&qb[qt * 128 + (c << 6)]);

    // opaque zero accumulator seed (compiler can't rematerialize as v_movs)
    float z0 = 0.f;
    asm volatile("" : "+v"(z0));
    const f32x4 fz = {z0, z0, z0, z0};

    const char* sbase = (const char*)(Sbf + (size_t)(bw << 6) * 128);
    const size_t toff = (size_t)threadIdx.x * 16;    // block stages 4KB/pair

    float t0[4], t1[4], t2[4];
    #pragma unroll
    for (int qt = 0; qt < 4; ++qt) { t0[qt] = -1e30f; t1[qt] = -1e30f; t2[qt] = -1e30f; }

    // prologue: stage pairs 0..3
    #pragma unroll
    for (int p = 0; p < 4; ++p)
        gload16(sbase + (size_t)p * 4096 + toff, &ring[(p << 8) + (wv << 6)]);

    // main loop: 32 pairs of s-tiles; stage 4 ahead, counted vmcnt, raw barrier
    for (int p = 0; p < 28; ++p) {
        gload16(sbase + (size_t)(p + 4) * 4096 + toff,
                &ring[(((p + 4) & 7) << 8) + (wv << 6)]);
        asm volatile("s_waitcnt vmcnt(4)" ::: "memory");
        __builtin_amdgcn_s_barrier();
        COMPUTE_PAIR(p & 7);
        __builtin_amdgcn_s_barrier();
    }
    // tail: everything staged; drain once, no more barriers needed
    asm volatile("s_waitcnt vmcnt(0)" ::: "memory");
    __builtin_amdgcn_s_barrier();
    #pragma unroll
    for (int p = 28; p < 32; ++p)
        COMPUTE_PAIR(p & 7);

    // merge top-3 across the 4 lane-groups sharing each q; apply rnq
    float s3 = 0.f;
    #pragma unroll
    for (int qt = 0; qt < 4; ++qt) {
        #pragma unroll
        for (int m = 16; m <= 32; m <<= 1) {
            float b0 = __shfl_xor(t0[qt], m);
            float b1 = __shfl_xor(t1[qt], m);
            float b2 = __shfl_xor(t2[qt], m);
            INS(b0, t0[qt], t1[qt], t2[qt]);
            INS(b1, t0[qt], t1[qt], t2[qt]);
            INS(b2, t0[qt], t1[qt], t2[qt]);
        }
        const int qg = (qc << 8) + (wv << 6) + (qt << 4) + (lane & 15);
        s3 += (t0[qt] + t1[qt] + t2[qt]) * rnq[(b << 10) + qg];
    }
    #pragma unroll
    for (int m = 1; m < 64; m <<= 1) s3 += __shfl_xor(s3, m);
    s3 *= 0.25f;                       // each q replicated over 4 lane-groups
    if (lane == 0) wsum[wv] = s3;
    __syncthreads();
    if (threadIdx.x == 0)
        partial[((size_t)bw << 2) + qc] = (wsum[0] + wsum[1]) + (wsum[2] + wsum[3]);
}

__global__ void finalize4(const float* __restrict__ partial, float* __restrict__ out) {
    int i = blockIdx.x * blockDim.x + threadIdx.x;
    if (i < 320)
        out[i] = (partial[4 * i] + partial[4 * i + 1]) +
                 (partial[4 * i + 2] + partial[4 * i + 3]);
}

// ============================ fallback path (round-2) ========================
__global__ void norms_kernel(const float* __restrict__ Q, const float* __restrict__ S,
                             float* __restrict__ rnq, float* __restrict__ rns) {
    int gid = blockIdx.x * blockDim.x + threadIdx.x;
    if (gid < 65536) {
        int b = gid >> 10, qi = gid & 1023;
        const float* p = Q + (size_t)b * 65536 + qi;
        float ss = 0.f;
        #pragma unroll
        for (int d = 0; d < 64; ++d) { float v = p[(size_t)d * 1024]; ss += v * v; }
        rnq[gid] = 1.0f / fmaxf(sqrtf(ss), 1e-12f);
    } else {
        int v = gid - 65536;
        int bw = v >> 10, si = v & 1023;
        const float* p = S + (size_t)bw * 65536 + si;
        float ss = 0.f;
        #pragma unroll
        for (int d = 0; d < 64; ++d) { float x = p[(size_t)d * 1024]; ss += x * x; }
        rns[v] = 1.0f / fmaxf(sqrtf(ss), 1e-12f);
    }
}

__global__ __launch_bounds__(512, 4) void knn_fb(
        const float* __restrict__ Q, const float* __restrict__ S,
        const float* __restrict__ rnq, const float* __restrict__ rns,
        float* __restrict__ partial) {
    __shared__ uint4 qfrag[16 * 128];
    __shared__ uint4 sfrag[2][4 * 128];
    __shared__ float wsum[8];

    const int qc = blockIdx.x, w = blockIdx.y, b = blockIdx.z;
    const int t = threadIdx.x, wv = t >> 6, lane = t & 63;

    const float* Qb   = Q + (size_t)b * 65536;
    const float* Sb   = S + (size_t)(b * 5 + w) * 65536;
    const float* rnqb = rnq + (b << 10);
    const float* rnsb = rns + ((b * 5 + w) << 10);

    bf16x8 bq[4][2];
    for (int ph = 0; ph < 2; ++ph) {
        for (int sub = 0; sub < 4; ++sub) {
            int qg = (qc << 9) + (ph << 8) + (sub << 6) + lane;
            float v[8];
            #pragma unroll
            for (int i = 0; i < 8; ++i)
                v[i] = Qb[(size_t)((wv << 3) + i) * 1024 + qg];
            qfrag[((sub << 2) + (lane >> 4)) * 128 + (wv << 4) + (lane & 15)] = pack8cvt(v);
        }
        __syncthreads();
        if ((wv >> 2) == ph) {
            #pragma unroll
            for (int qt = 0; qt < 4; ++qt)
                #pragma unroll
                for (int c = 0; c < 2; ++c)
                    bq[qt][c] = *reinterpret_cast<const bf16x8*>(
                        &qfrag[(((wv & 3) << 2) + qt) * 128 + (c << 6) + lane]);
        }
        __syncthreads();
    }

    {
        float sv[8]; float rs = rnsb[lane];
        #pragma unroll
        for (int i = 0; i < 8; ++i)
            sv[i] = Sb[(size_t)((wv << 3) + i) * 1024 + lane] * rs;
        sfrag[0][(lane >> 4) * 128 + (wv << 4) + (lane & 15)] = pack8cvt(sv);
    }
    __syncthreads();

    float t0[4], t1[4], t2[4];
    #pragma unroll
    for (int qt = 0; qt < 4; ++qt) { t0[qt] = -1e30f; t1[qt] = -1e30f; t2[qt] = -1e30f; }
    int cur = 0;
    const float* sp = Sb + ((wv << 3) << 10) + lane;

    for (int blk = 0; blk < 16; ++blk) {
        float sv[8]; float rs;
        if (blk < 15) {
            const int sb_ = (blk + 1) << 6;
            rs = rnsb[sb_ + lane];
            #pragma unroll
            for (int i = 0; i < 8; ++i)
                sv[i] = sp[(size_t)(i << 10) + sb_];
        }
        #pragma unroll
        for (int st = 0; st < 4; ++st) {
            bf16x8 a0 = *reinterpret_cast<const bf16x8*>(&sfrag[cur][st * 128 + lane]);
            bf16x8 a1 = *reinterpret_cast<const bf16x8*>(&sfrag[cur][st * 128 + 64 + lane]);
            #pragma unroll
            for (int qt = 0; qt < 4; ++qt) {
                f32x4 c = {0.f, 0.f, 0.f, 0.f};
                c = __builtin_amdgcn_mfma_f32_16x16x32_bf16(a0, bq[qt][0], c, 0, 0, 0);
                c = __builtin_amdgcn_mfma_f32_16x16x32_bf16(a1, bq[qt][1], c, 0, 0, 0);
                #pragma unroll
                for (int j = 0; j < 4; ++j)
                    INS(c[j], t0[qt], t1[qt], t2[qt]);
            }
        }
        if (blk < 15) {
            #pragma unroll
            for (int i = 0; i < 8; ++i) sv[i] *= rs;
            sfrag[cur ^ 1][(lane >> 4) * 128 + (wv << 4) + (lane & 15)] = pack8cvt(sv);
        }
        __syncthreads();
        cur ^= 1;
    }

    float s3 = 0.f;
    #pragma unroll
    for (int qt = 0; qt < 4; ++qt) {
        #pragma unroll
        for (int m = 16; m <= 32; m <<= 1) {
            float b0 = __shfl_xor(t0[qt], m);
            float b1 = __shfl_xor(t1[qt], m);
            float b2 = __shfl_xor(t2[qt], m);
            INS(b0, t0[qt], t1[qt], t2[qt]);
            INS(b1, t0[qt], t1[qt], t2[qt]);
            INS(b2, t0[qt], t1[qt], t2[qt]);
        }
        int qg = (qc << 9) + (wv << 6) + (qt << 4) + (lane & 15);
        s3 += (t0[qt] + t1[qt] + t2[qt]) * rnqb[qg];
    }
    #pragma unroll
    for (int m = 1; m < 64; m <<= 1) s3 += __shfl_xor(s3, m);
    s3 *= 0.25f;
    if (lane == 0) wsum[wv] = s3;
    __syncthreads();
    if (t == 0) {
        float acc = 0.f;
        #pragma unroll
        for (int i = 0; i < 8; ++i) acc += wsum[i];
        partial[((b * 5 + w) << 1) + qc] = acc;
    }
}

__global__ void finalize2(const float* __restrict__ partial, float* __restrict__ out) {
    int i = blockIdx.x * blockDim.x + threadIdx.x;
    if (i < 320)
        out[i] = partial[2 * i] + partial[2 * i + 1];
}

// =============================================================================
extern "C" void kernel_launch(void* const* d_in, const int* in_sizes, int n_in,
                              void* d_out, int out_size, void* d_ws, size_t ws_size,
                              hipStream_t stream) {
    const float* Q = (const float*)d_in[0];   // (64,64,32,32)
    const float* S = (const float*)d_in[1];   // (64,5,64,1024)
    float* out = (float*)d_out;               // (64,5)

    // fast-path ws: Qbf 8 MB | Sbf 41.9 MB | rnq 256 KB | partial 5 KB
    const size_t QBF = 8388608ull, SBF = 41943040ull, RNQ = 262144ull;
    const size_t NEED = QBF + SBF + RNQ + 5120ull;
    if (ws_size >= NEED) {
        char* base = (char*)d_ws;
        uint4* Qbf     = (uint4*)base;
        uint4* Sbf     = (uint4*)(base + QBF);
        float* rnq     = (float*)(base + QBF + SBF);
        float* partial = (float*)(base + QBF + SBF + RNQ);
        prep_all<<<1536, 256, 0, stream>>>(Q, S, Qbf, Sbf, rnq);
        knn_main<<<1280, 256, 0, stream>>>(Qbf, Sbf, rnq, partial);
        finalize4<<<2, 256, 0, stream>>>(partial, out);
    } else {
        float* rnq = (float*)d_ws;
        float* rns = rnq + 65536;
        float* partial = rns + 327680;
        norms_kernel<<<(65536 + 327680) / 256, 256, 0, stream>>>(Q, S, rnq, rns);
        knn_fb<<<dim3(2, 5, 64), 512, 0, stream>>>(Q, S, rnq, rns, partial);
        finalize2<<<2, 256, 0, stream>>>(partial, out);
    }
}

// Round 9
// 92.033 us; speedup vs baseline: 1.1001x; 1.0194x over previous
//
#include <hip/hip_runtime.h>
#include <hip/hip_bf16.h>

// LocalKNN: B=64, Way=5, D=64, Nq=1024, Ns=1024, K=3.
// out[b,w] = sum_q rnq[q] * sum(top3_s( <q_bq, shat_bws> ))
// Round 9: cross-tile accumulator pipeline (T15). Phase t: mfma(tile t)->cX,
// INS(tile t-1) on cY (two named sets, parity-alternated). Every INS reads
// results >=1 phase old -> no mfma->VALU hazard stalls, and the overlapping
// cA/cB lifetimes force the compiler to keep both live (r8's VGPR=60 proved
// it re-serialized the batched schedule to save registers).
// One barrier per pair (ring distance 5 < 8 bounds drift), vmcnt(4) counted.

using bf16x8 = __attribute__((ext_vector_type(8))) short;  // 8 bf16 = 4 VGPRs
using f32x4  = __attribute__((ext_vector_type(4))) float;

__device__ inline unsigned cvt_pk_bf16(float lo, float hi) {
    unsigned r;
    asm("v_cvt_pk_bf16_f32 %0, %1, %2" : "=v"(r) : "v"(lo), "v"(hi));
    return r;
}

__device__ inline uint4 pack8cvt(const float* v) {
    uint4 r;
    r.x = cvt_pk_bf16(v[0], v[1]);
    r.y = cvt_pk_bf16(v[2], v[3]);
    r.z = cvt_pk_bf16(v[4], v[5]);
    r.w = cvt_pk_bf16(v[6], v[7]);
    return r;
}

// branchless insert of v into sorted top-3 (t0>=t1>=t2): 1 max + 2 med3
#define INS(v, T0, T1, T2) do {                         \
    float _v = (v);                                     \
    float _n0 = fmaxf((T0), _v);                        \
    float _n1 = __builtin_amdgcn_fmed3f(_v, (T0), (T1));\
    float _n2 = __builtin_amdgcn_fmed3f(_v, (T1), (T2));\
    (T0) = _n0; (T1) = _n1; (T2) = _n2;                 \
} while (0)

// async 16B/lane global->LDS (LDS dest = wave-uniform base + lane*16)
__device__ inline void gload16(const void* g, void* lds) {
    __builtin_amdgcn_global_load_lds(
        (const __attribute__((address_space(1))) unsigned int*)g,
        (__attribute__((address_space(3))) unsigned int*)lds,
        16, 0, 0);
}

// ============================= fast path =====================================
// Fragment layout: per 16-col tile, 128 uint4 slots; slot h*16 + r holds
// column (tile*16+r)'s elements d = 8h..8h+7 as 4 packed bf16-pairs.
// MFMA read: slot c*64 + lane -> lane holds col r=lane&15, k = c*32 + (lane>>4)*8 + j.

// ---- prep_all: raw Q/S -> bf16 fragments (+ rnq) ----------------------------
__global__ __launch_bounds__(256) void prep_all(const float* __restrict__ Q,
                                                const float* __restrict__ S,
                                                uint4* __restrict__ Qbf,
                                                uint4* __restrict__ Sbf,
                                                float* __restrict__ rnq) {
    const int blk = blockIdx.x;
    if (blk < 256) {
        const int b = blk >> 2;
        const int col = ((blk & 3) << 8) + threadIdx.x;      // q in 0..1023
        const float* p = Q + (size_t)b * 65536 + col;
        float v[64];
        #pragma unroll
        for (int d = 0; d < 64; ++d) v[d] = p[(size_t)d << 10];
        float ss = 0.f;
        #pragma unroll
        for (int d = 0; d < 64; ++d) ss += v[d] * v[d];
        rnq[(b << 10) + col] = 1.0f / fmaxf(sqrtf(ss), 1e-12f);
        uint4* ob = Qbf + ((size_t)(b << 6) + (col >> 4)) * 128 + (col & 15);
        #pragma unroll
        for (int h = 0; h < 8; ++h)
            ob[h << 4] = pack8cvt(&v[h << 3]);
    } else {
        const int bw = (blk - 256) >> 2;
        const int col = ((blk & 3) << 8) + threadIdx.x;      // s in 0..1023
        const float* p = S + (size_t)bw * 65536 + col;
        float v[64];
        #pragma unroll
        for (int d = 0; d < 64; ++d) v[d] = p[(size_t)d << 10];
        float ss = 0.f;
        #pragma unroll
        for (int d = 0; d < 64; ++d) ss += v[d] * v[d];
        const float rs = 1.0f / fmaxf(sqrtf(ss), 1e-12f);
        #pragma unroll
        for (int d = 0; d < 64; ++d) v[d] *= rs;
        uint4* ob = Sbf + ((size_t)(bw << 6) + (col >> 4)) * 128 + (col & 15);
        #pragma unroll
        for (int h = 0; h < 8; ++h)
            ob[h << 4] = pack8cvt(&v[h << 3]);
    }
}

// 8 MFMAs for one 16-s tile into c[0..3] (one per q-tile), seeded from opaque 0
__device__ __forceinline__ void mfma_tile(const uint4* sp, int lane,
                                          const bf16x8 (&bq)[4][2],
                                          const f32x4& fz, f32x4* c) {
    bf16x8 a0 = *reinterpret_cast<const bf16x8*>(&sp[lane]);
    bf16x8 a1 = *reinterpret_cast<const bf16x8*>(&sp[64 + lane]);
    #pragma unroll
    for (int qt = 0; qt < 4; ++qt) {
        c[qt] = __builtin_amdgcn_mfma_f32_16x16x32_bf16(a0, bq[qt][0], fz, 0, 0, 0);
        c[qt] = __builtin_amdgcn_mfma_f32_16x16x32_bf16(a1, bq[qt][1], c[qt], 0, 0, 0);
    }
}

// 48 INS ops consuming one tile's accumulators (values >=1 phase old)
__device__ __forceinline__ void ins_tile(const f32x4* c,
                                         float (&t0)[4], float (&t1)[4], float (&t2)[4]) {
    #pragma unroll
    for (int qt = 0; qt < 4; ++qt)
        #pragma unroll
        for (int j = 0; j < 4; ++j)
            INS(c[qt][j], t0[qt], t1[qt], t2[qt]);
}

// ---- main: LDS-pipelined fused GEMM + top-3, cross-tile acc pipeline --------
// 1-D grid 1280 (logical l: qc = l&3, bw = l>>2), block = 256 (4 waves).
// S streams through an 8-slot LDS ring of tile-PAIRS (4KB), staged 4 ahead.
__global__ __launch_bounds__(256, 4) void knn_main(const uint4* __restrict__ Qbf,
                                                   const uint4* __restrict__ Sbf,
                                                   const float* __restrict__ rnq,
                                                   float* __restrict__ partial) {
    __shared__ uint4 ring[8 * 256];     // 8 pair-slots x 4 KB = 32 KB
    __shared__ float wsum[4];
    const int lin = blockIdx.x;
    const int l   = (lin & 7) * 160 + (lin >> 3);   // 1280 = 8*160, bijective
    const int qc  = l & 3;
    const int bw  = l >> 2;                          // b*5 + w
    const int b   = bw / 5;
    const int wv = threadIdx.x >> 6, lane = threadIdx.x & 63;

    // Q fragments: one-time global read
    const uint4* qb = Qbf + ((size_t)(b << 6) + (qc << 4) + (wv << 2)) * 128 + lane;
    bf16x8 bq[4][2];
    #pragma unroll
    for (int qt = 0; qt < 4; ++qt)
        #pragma unroll
        for (int c = 0; c < 2; ++c)
            bq[qt][c] = *reinterpret_cast<const bf16x8*>(&qb[qt * 128 + (c << 6)]);

    // opaque zero accumulator seed (not rematerializable as v_movs)
    float z0 = 0.f;
    asm volatile("" : "+v"(z0));
    const f32x4 fz = {z0, z0, z0, z0};

    const char* sbase = (const char*)(Sbf + (size_t)(bw << 6) * 128);
    const size_t toff = (size_t)threadIdx.x * 16;    // block stages 4KB/pair

    float t0[4], t1[4], t2[4];
    #pragma unroll
    for (int qt = 0; qt < 4; ++qt) { t0[qt] = -1e30f; t1[qt] = -1e30f; t2[qt] = -1e30f; }

    f32x4 cA[4], cB[4];   // the two pipeline stages (even tiles -> cA, odd -> cB)

    // prologue: stage pairs 0..3
    #pragma unroll
    for (int p = 0; p < 4; ++p)
        gload16(sbase + (size_t)p * 4096 + toff, &ring[(p << 8) + (wv << 6)]);

    // pair 0 (no INS yet): fill both pipeline stages
    gload16(sbase + 4 * 4096 + toff, &ring[(4 << 8) + (wv << 6)]);
    asm volatile("s_waitcnt vmcnt(4)" ::: "memory");
    __builtin_amdgcn_s_barrier();
    mfma_tile(&ring[0], lane, bq, fz, cA);        // tile 0
    mfma_tile(&ring[128], lane, bq, fz, cB);      // tile 1

    // pairs 1..27: stage p+4, counted vmcnt, ONE barrier, 2 pipelined phases
    for (int p = 1; p <= 27; ++p) {
        gload16(sbase + (size_t)(p + 4) * 4096 + toff,
                &ring[(((p + 4) & 7) << 8) + (wv << 6)]);
        asm volatile("s_waitcnt vmcnt(4)" ::: "memory");
        __builtin_amdgcn_s_barrier();
        const uint4* sp = &ring[((p & 7) << 8)];
        mfma_tile(sp, lane, bq, fz, cA);          // tile 2p   -> cA
        ins_tile(cB, t0, t1, t2);                 // tile 2p-1 (old cB)
        mfma_tile(sp + 128, lane, bq, fz, cB);    // tile 2p+1 -> cB
        ins_tile(cA, t0, t1, t2);                 // tile 2p
    }
    // tail: pairs 28..31 fully staged; drain once, no more barriers
    asm volatile("s_waitcnt vmcnt(0)" ::: "memory");
    __builtin_amdgcn_s_barrier();
    #pragma unroll
    for (int p = 28; p <= 31; ++p) {
        const uint4* sp = &ring[((p & 7) << 8)];
        mfma_tile(sp, lane, bq, fz, cA);
        ins_tile(cB, t0, t1, t2);
        mfma_tile(sp + 128, lane, bq, fz, cB);
        ins_tile(cA, t0, t1, t2);
    }
    ins_tile(cB, t0, t1, t2);                     // tile 63

    // merge top-3 across the 4 lane-groups sharing each q; apply rnq
    float s3 = 0.f;
    #pragma unroll
    for (int qt = 0; qt < 4; ++qt) {
        #pragma unroll
        for (int m = 16; m <= 32; m <<= 1) {
            float b0 = __shfl_xor(t0[qt], m);
            float b1 = __shfl_xor(t1[qt], m);
            float b2 = __shfl_xor(t2[qt], m);
            INS(b0, t0[qt], t1[qt], t2[qt]);
            INS(b1, t0[qt], t1[qt], t2[qt]);
            INS(b2, t0[qt], t1[qt], t2[qt]);
        }
        const int qg = (qc << 8) + (wv << 6) + (qt << 4) + (lane & 15);
        s3 += (t0[qt] + t1[qt] + t2[qt]) * rnq[(b << 10) + qg];
    }
    #pragma unroll
    for (int m = 1; m < 64; m <<= 1) s3 += __shfl_xor(s3, m);
    s3 *= 0.25f;                       // each q replicated over 4 lane-groups
    if (lane == 0) wsum[wv] = s3;
    __syncthreads();
    if (threadIdx.x == 0)
        partial[((size_t)bw << 2) + qc] = (wsum[0] + wsum[1]) + (wsum[2] + wsum[3]);
}

__global__ void finalize4(const float* __restrict__ partial, float* __restrict__ out) {
    int i = blockIdx.x * blockDim.x + threadIdx.x;
    if (i < 320)
        out[i] = (partial[4 * i] + partial[4 * i + 1]) +
                 (partial[4 * i + 2] + partial[4 * i + 3]);
}

// ============================ fallback path (round-2) ========================
__global__ void norms_kernel(const float* __restrict__ Q, const float* __restrict__ S,
                             float* __restrict__ rnq, float* __restrict__ rns) {
    int gid = blockIdx.x * blockDim.x + threadIdx.x;
    if (gid < 65536) {
        int b = gid >> 10, qi = gid & 1023;
        const float* p = Q + (size_t)b * 65536 + qi;
        float ss = 0.f;
        #pragma unroll
        for (int d = 0; d < 64; ++d) { float v = p[(size_t)d * 1024]; ss += v * v; }
        rnq[gid] = 1.0f / fmaxf(sqrtf(ss), 1e-12f);
    } else {
        int v = gid - 65536;
        int bw = v >> 10, si = v & 1023;
        const float* p = S + (size_t)bw * 65536 + si;
        float ss = 0.f;
        #pragma unroll
        for (int d = 0; d < 64; ++d) { float x = p[(size_t)d * 1024]; ss += x * x; }
        rns[v] = 1.0f / fmaxf(sqrtf(ss), 1e-12f);
    }
}

__global__ __launch_bounds__(512, 4) void knn_fb(
        const float* __restrict__ Q, const float* __restrict__ S,
        const float* __restrict__ rnq, const float* __restrict__ rns,
        float* __restrict__ partial) {
    __shared__ uint4 qfrag[16 * 128];
    __shared__ uint4 sfrag[2][4 * 128];
    __shared__ float wsum[8];

    const int qc = blockIdx.x, w = blockIdx.y, b = blockIdx.z;
    const int t = threadIdx.x, wv = t >> 6, lane = t & 63;

    const float* Qb   = Q + (size_t)b * 65536;
    const float* Sb   = S + (size_t)(b * 5 + w) * 65536;
    const float* rnqb = rnq + (b << 10);
    const float* rnsb = rns + ((b * 5 + w) << 10);

    bf16x8 bq[4][2];
    for (int ph = 0; ph < 2; ++ph) {
        for (int sub = 0; sub < 4; ++sub) {
            int qg = (qc << 9) + (ph << 8) + (sub << 6) + lane;
            float v[8];
            #pragma unroll
            for (int i = 0; i < 8; ++i)
                v[i] = Qb[(size_t)((wv << 3) + i) * 1024 + qg];
            qfrag[((sub << 2) + (lane >> 4)) * 128 + (wv << 4) + (lane & 15)] = pack8cvt(v);
        }
        __syncthreads();
        if ((wv >> 2) == ph) {
            #pragma unroll
            for (int qt = 0; qt < 4; ++qt)
                #pragma unroll
                for (int c = 0; c < 2; ++c)
                    bq[qt][c] = *reinterpret_cast<const bf16x8*>(
                        &qfrag[(((wv & 3) << 2) + qt) * 128 + (c << 6) + lane]);
        }
        __syncthreads();
    }

    {
        float sv[8]; float rs = rnsb[lane];
        #pragma unroll
        for (int i = 0; i < 8; ++i)
            sv[i] = Sb[(size_t)((wv << 3) + i) * 1024 + lane] * rs;
        sfrag[0][(lane >> 4) * 128 + (wv << 4) + (lane & 15)] = pack8cvt(sv);
    }
    __syncthreads();

    float t0[4], t1[4], t2[4];
    #pragma unroll
    for (int qt = 0; qt < 4; ++qt) { t0[qt] = -1e30f; t1[qt] = -1e30f; t2[qt] = -1e30f; }
    int cur = 0;
    const float* sp = Sb + ((wv << 3) << 10) + lane;

    for (int blk = 0; blk < 16; ++blk) {
        float sv[8]; float rs;
        if (blk < 15) {
            const int sb_ = (blk + 1) << 6;
            rs = rnsb[sb_ + lane];
            #pragma unroll
            for (int i = 0; i < 8; ++i)
                sv[i] = sp[(size_t)(i << 10) + sb_];
        }
        #pragma unroll
        for (int st = 0; st < 4; ++st) {
            bf16x8 a0 = *reinterpret_cast<const bf16x8*>(&sfrag[cur][st * 128 + lane]);
            bf16x8 a1 = *reinterpret_cast<const bf16x8*>(&sfrag[cur][st * 128 + 64 + lane]);
            #pragma unroll
            for (int qt = 0; qt < 4; ++qt) {
                f32x4 c = {0.f, 0.f, 0.f, 0.f};
                c = __builtin_amdgcn_mfma_f32_16x16x32_bf16(a0, bq[qt][0], c, 0, 0, 0);
                c = __builtin_amdgcn_mfma_f32_16x16x32_bf16(a1, bq[qt][1], c, 0, 0, 0);
                #pragma unroll
                for (int j = 0; j < 4; ++j)
                    INS(c[j], t0[qt], t1[qt], t2[qt]);
            }
        }
        if (blk < 15) {
            #pragma unroll
            for (int i = 0; i < 8; ++i) sv[i] *= rs;
            sfrag[cur ^ 1][(lane >> 4) * 128 + (wv << 4) + (lane & 15)] = pack8cvt(sv);
        }
        __syncthreads();
        cur ^= 1;
    }

    float s3 = 0.f;
    #pragma unroll
    for (int qt = 0; qt < 4; ++qt) {
        #pragma unroll
        for (int m = 16; m <= 32; m <<= 1) {
            float b0 = __shfl_xor(t0[qt], m);
            float b1 = __shfl_xor(t1[qt], m);
            float b2 = __shfl_xor(t2[qt], m);
            INS(b0, t0[qt], t1[qt], t2[qt]);
            INS(b1, t0[qt], t1[qt], t2[qt]);
            INS(b2, t0[qt], t1[qt], t2[qt]);
        }
        int qg = (qc << 9) + (wv << 6) + (qt << 4) + (lane & 15);
        s3 += (t0[qt] + t1[qt] + t2[qt]) * rnqb[qg];
    }
    #pragma unroll
    for (int m = 1; m < 64; m <<= 1) s3 += __shfl_xor(s3, m);
    s3 *= 0.25f;
    if (lane == 0) wsum[wv] = s3;
    __syncthreads();
    if (t == 0) {
        float acc = 0.f;
        #pragma unroll
        for (int i = 0; i < 8; ++i) acc += wsum[i];
        partial[((b * 5 + w) << 1) + qc] = acc;
    }
}

__global__ void finalize2(const float* __restrict__ partial, float* __restrict__ out) {
    int i = blockIdx.x * blockDim.x + threadIdx.x;
    if (i < 320)
        out[i] = partial[2 * i] + partial[2 * i + 1];
}

// =============================================================================
extern "C" void kernel_launch(void* const* d_in, const int* in_sizes, int n_in,
                              void* d_out, int out_size, void* d_ws, size_t ws_size,
                              hipStream_t stream) {
    const float* Q = (const float*)d_in[0];   // (64,64,32,32)
    const float* S = (const float*)d_in[1];   // (64,5,64,1024)
    float* out = (float*)d_out;               // (64,5)

    // fast-path ws: Qbf 8 MB | Sbf 41.9 MB | rnq 256 KB | partial 5 KB
    const size_t QBF = 8388608ull, SBF = 41943040ull, RNQ = 262144ull;
    const size_t NEED = QBF + SBF + RNQ + 5120ull;
    if (ws_size >= NEED) {
        char* base = (char*)d_ws;
        uint4* Qbf     = (uint4*)base;
        uint4* Sbf     = (uint4*)(base + QBF);
        float* rnq     = (float*)(base + QBF + SBF);
        float* partial = (float*)(base + QBF + SBF + RNQ);
        prep_all<<<1536, 256, 0, stream>>>(Q, S, Qbf, Sbf, rnq);
        knn_main<<<1280, 256, 0, stream>>>(Qbf, Sbf, rnq, partial);
        finalize4<<<2, 256, 0, stream>>>(partial, out);
    } else {
        float* rnq = (float*)d_ws;
        float* rns = rnq + 65536;
        float* partial = rns + 327680;
        norms_kernel<<<(65536 + 327680) / 256, 256, 0, stream>>>(Q, S, rnq, rns);
        knn_fb<<<dim3(2, 5, 64), 512, 0, stream>>>(Q, S, rnq, rns, partial);
        finalize2<<<2, 256, 0, stream>>>(partial, out);
    }
}